// Round 12
// baseline (140.200 us; speedup 1.0000x reference)
//
#include <hip/hip_runtime.h>
#include <cstdint>
#include <cstddef>

#define IMGW 640
#define HPW  160
#define BATCH 2
#define NG   2
#define CPG  48

typedef _Float16 h2v __attribute__((ext_vector_type(2)));
#if defined(__has_builtin)
#if __has_builtin(__builtin_amdgcn_fdot2)
#define HAVE_FDOT2 1
#endif
#endif

__device__ __forceinline__ float fdot2f(float a, float b, float c) {
#if HAVE_FDOT2
    return __builtin_amdgcn_fdot2(__builtin_bit_cast(h2v, a),
                                  __builtin_bit_cast(h2v, b), c, false);
#else
    h2v av = __builtin_bit_cast(h2v, a), bv = __builtin_bit_cast(h2v, b);
    return fmaf((float)av.x, (float)bv.x, fmaf((float)av.y, (float)bv.y, c));
#endif
}

__device__ __forceinline__ float packh2(float a, float b) {
    h2v p; p.x = (_Float16)a; p.y = (_Float16)b;
    return __builtin_bit_cast(float, p);
}

// tiny-|h| GELU: h*(0.5 + phi0*h*(1 - h^2/6)), clamp poly input to |h|<=1.
__device__ __forceinline__ float gelu_poly(float h) {
    float hc = fminf(fmaxf(h, -1.0f), 1.0f);
    float q = fmaf(hc * hc, -0.1666666667f, 1.0f);
    float r = fmaf(0.3989422804f * hc, q, 0.5f);
    return h * r;
}

__device__ __forceinline__ float fast_tanh(float t) {
    float u = __builtin_amdgcn_exp2f(2.8853900818f * t);    // e^{2t}
    return 1.0f - 2.0f * __builtin_amdgcn_rcpf(u + 1.0f);
}

// ---------------------------------------------------------------------------
// Kernel 1: fold embed into ph_w1, pack per-channel weights as 16 dwords:
//  dw[c*4+j] = f16x2( W[e,tap 2j,c], W[e,tap 2j+1,c] )    c=0..2, j=0..3
//  dw[12]    = f16x2( W[e,tap8,c0], W[e,tap8,c1] )
//  dw[13]    = W[e,tap8,c2] (fp32)
//  dw[14]    = bias_int[e] = ph_b1[e] + sum_k B1f[e,k]
//  Also writes B1f[e*9+k] (border-bias table).
// ---------------------------------------------------------------------------
__global__ void fold_kernel(const float* __restrict__ ph_w1,
                            const float* __restrict__ embed_w,
                            const float* __restrict__ embed_b,
                            const float* __restrict__ ph_b1,
                            float* __restrict__ w1h,
                            float* __restrict__ B1f) {
    int e = blockIdx.x * 128 + threadIdx.x;
    if (e >= 96) return;
    float g[27];   // [k*3+c]
    float bf[9];
#pragma unroll
    for (int k = 0; k < 27; ++k) g[k] = 0.f;
#pragma unroll
    for (int k = 0; k < 9; ++k) bf[k] = 0.f;
    for (int c96 = 0; c96 < 96; ++c96) {
        const float* w = ph_w1 + e * 864 + c96 * 9;
        float e0 = embed_w[c96 * 3], e1 = embed_w[c96 * 3 + 1], e2 = embed_w[c96 * 3 + 2];
        float eb = embed_b[c96];
#pragma unroll
        for (int k = 0; k < 9; ++k) {
            float wk = w[k];
            g[k * 3 + 0] = fmaf(wk, e0, g[k * 3 + 0]);
            g[k * 3 + 1] = fmaf(wk, e1, g[k * 3 + 1]);
            g[k * 3 + 2] = fmaf(wk, e2, g[k * 3 + 2]);
            bf[k] = fmaf(wk, eb, bf[k]);
        }
    }
    float bi = ph_b1[e];
#pragma unroll
    for (int k = 0; k < 9; ++k) { B1f[e * 9 + k] = bf[k]; bi += bf[k]; }
    float* dst = w1h + e * 16;
#pragma unroll
    for (int c = 0; c < 3; ++c)
#pragma unroll
        for (int j = 0; j < 4; ++j)
            dst[c * 4 + j] = packh2(g[(2 * j) * 3 + c], g[(2 * j + 1) * 3 + c]);
    dst[12] = packh2(g[8 * 3 + 0], g[8 * 3 + 1]);
    dst[13] = g[8 * 3 + 2];
    dst[14] = bi;
    dst[15] = 0.f;
}

// ---------------------------------------------------------------------------
// Kernel 2: fused conv1(folded, f16-dot2) + poly GELU + conv2(4x4 s4), NG=2.
// ONE PIXEL PER THREAD: block = 16x16 px = 4x4 patches, 256 threads,
// 48 of 96 channels (g = bid&1). wave = patch row, lane = q*16+pi.
// conv1 weights + border-bias in LDS: wave-uniform ds_read_b128 broadcasts
// straight into VGPRs (R10: s_load weights -> suspected SGPR->VGPR mov per
// VOP3P dot2, ~2x instr inflation). conv2 weights LDS stride 293 (R10 fix).
// ---------------------------------------------------------------------------
__global__ __launch_bounds__(256) void params_kernel(
    const float* __restrict__ x,
    const float* __restrict__ w1h,
    const float* __restrict__ B1f,
    const float* __restrict__ ph_b1,
    const float* __restrict__ ph_w2,
    float* __restrict__ part) {
    __shared__ float xs[3 * 18 * 18];     // 3888 B: 16x16 tile + 1px halo
    __shared__ float w2l[16 * 293];       // 18752 B: [pi][e*3+ch], stride 293
    __shared__ float w1s[96 * 16];        // 6144 B: packed conv1 weights
    __shared__ float b1s[96 * 9];         // 3456 B: border-bias table

    int bid = blockIdx.x;                 // 2 * 1600 * NG
    int g = bid & (NG - 1);
    int tile = bid >> 1;
    int b = tile / 1600;
    int rem = tile - b * 1600;
    int th = rem / 40, tw = rem - th * 40;
    int y0 = th * 16, x0 = tw * 16;
    int tid = threadIdx.x;

    const float* xb = x + (size_t)b * 3 * 409600;
    for (int l = tid; l < 972; l += 256) {
        int c = l / 324;
        int r2 = l - c * 324;
        int ry = r2 / 18, rx = r2 - ry * 18;
        int gy = y0 - 1 + ry, gx = x0 - 1 + rx;
        float v = 0.f;
        if (gy >= 0 && gy < IMGW && gx >= 0 && gx < IMGW)
            v = xb[c * 409600 + gy * 640 + gx];
        xs[l] = v;
    }
    for (int l = tid; l < 4608; l += 256) {
        int ch = l / 1536;
        int r2 = l - ch * 1536;
        int e = r2 >> 4, pi = r2 & 15;
        w2l[pi * 293 + e * 3 + ch] = ph_w2[l];
    }
    for (int l = tid; l < 1536; l += 256) w1s[l] = w1h[l];
    for (int l = tid; l < 864; l += 256) b1s[l] = B1f[l];
    __syncthreads();

    int w = tid >> 6, lane = tid & 63;
    int q = lane >> 4, pi = lane & 15;
    int py = pi >> 2, px = pi & 3;
    int ty = w * 4 + py, tx = q * 4 + px;

    // load 3x3x3 window and pack to f16 pairs (order matches fold layout)
    float xpk[13];
    float x8c2;
    {
        float win[27];
#pragma unroll
        for (int c = 0; c < 3; ++c)
#pragma unroll
            for (int dy = 0; dy < 3; ++dy)
#pragma unroll
                for (int dx = 0; dx < 3; ++dx)
                    win[c * 9 + dy * 3 + dx] = xs[c * 324 + (ty + dy) * 18 + (tx + dx)];
#pragma unroll
        for (int c = 0; c < 3; ++c)
#pragma unroll
            for (int j = 0; j < 4; ++j)
                xpk[c * 4 + j] = packh2(win[c * 9 + 2 * j], win[c * 9 + 2 * j + 1]);
        xpk[12] = packh2(win[8], win[9 + 8]);
        x8c2 = win[18 + 8];
    }
#pragma unroll
    for (int k = 0; k < 13; ++k) asm volatile("" : "+v"(xpk[k]));
    asm volatile("" : "+v"(x8c2));

    float s0 = 0.f, s1 = 0.f, s2 = 0.f;
    const int wbase = pi * 293;
    bool borderBlk = (th == 0) || (tw == 0) || (th == 39) || (tw == 39);
    int e0 = g * CPG;

    if (!borderBlk) {
#pragma unroll 2
        for (int e = e0; e < e0 + CPG; ++e) {
            const float4* u4 = reinterpret_cast<const float4*>(&w1s[e * 16]);
            float4 A = u4[0], B = u4[1], C = u4[2], D = u4[3];
            float accA = fdot2f(A.w, xpk[3], D.z);
            accA = fdot2f(A.z, xpk[2], accA);
            accA = fdot2f(A.y, xpk[1], accA);
            accA = fdot2f(A.x, xpk[0], accA);
            float accB = fdot2f(D.x, xpk[12], D.y * x8c2);
            accB = fdot2f(B.w, xpk[7], accB);
            accB = fdot2f(B.z, xpk[6], accB);
            accB = fdot2f(B.y, xpk[5], accB);
            accB = fdot2f(B.x, xpk[4], accB);
            float accC = fdot2f(C.w, xpk[11], 0.f);
            accC = fdot2f(C.z, xpk[10], accC);
            accC = fdot2f(C.y, xpk[9], accC);
            accC = fdot2f(C.x, xpk[8], accC);
            float h = (accA + accB) + accC;
            float gl = gelu_poly(h);
            s0 = fmaf(w2l[wbase + e * 3 + 0], gl, s0);
            s1 = fmaf(w2l[wbase + e * 3 + 1], gl, s1);
            s2 = fmaf(w2l[wbase + e * 3 + 2], gl, s2);
        }
    } else {
        float m[9];
        int gy0 = y0 + ty - 1, gx0 = x0 + tx - 1;
#pragma unroll
        for (int ky = 0; ky < 3; ++ky)
#pragma unroll
            for (int kx = 0; kx < 3; ++kx) {
                int iy = gy0 + ky, ix = gx0 + kx;
                m[ky * 3 + kx] = (iy >= 0 && iy < IMGW && ix >= 0 && ix < IMGW) ? 1.f : 0.f;
            }
        for (int e = e0; e < e0 + CPG; ++e) {
            const float4* u4 = reinterpret_cast<const float4*>(&w1s[e * 16]);
            float4 A = u4[0], B = u4[1], C = u4[2], D = u4[3];
            float bb = ph_b1[e];
#pragma unroll
            for (int k = 0; k < 9; ++k)
                bb = fmaf(m[k], b1s[e * 9 + k], bb);
            float accA = fdot2f(A.w, xpk[3], bb);
            accA = fdot2f(A.z, xpk[2], accA);
            accA = fdot2f(A.y, xpk[1], accA);
            accA = fdot2f(A.x, xpk[0], accA);
            float accB = fdot2f(D.x, xpk[12], D.y * x8c2);
            accB = fdot2f(B.w, xpk[7], accB);
            accB = fdot2f(B.z, xpk[6], accB);
            accB = fdot2f(B.y, xpk[5], accB);
            accB = fdot2f(B.x, xpk[4], accB);
            float accC = fdot2f(C.w, xpk[11], 0.f);
            accC = fdot2f(C.z, xpk[10], accC);
            accC = fdot2f(C.y, xpk[9], accC);
            accC = fdot2f(C.x, xpk[8], accC);
            float h = (accA + accB) + accC;
            float gl = gelu_poly(h);
            s0 = fmaf(w2l[wbase + e * 3 + 0], gl, s0);
            s1 = fmaf(w2l[wbase + e * 3 + 1], gl, s1);
            s2 = fmaf(w2l[wbase + e * 3 + 2], gl, s2);
        }
    }

    // reduce conv2 over the 16 pixels of each patch (one 16-lane segment)
#pragma unroll
    for (int mm = 1; mm < 16; mm <<= 1) {
        s0 += __shfl_xor(s0, mm, 16);
        s1 += __shfl_xor(s1, mm, 16);
        s2 += __shfl_xor(s2, mm, 16);
    }

    if (pi == 0) {
        int hp = th * 4 + w, wp = tw * 4 + q;
        size_t o = ((size_t)(g * 2 + b) * 3) * 25600 + (size_t)hp * 160 + wp;
        part[o]             = s0;
        part[o + 25600]     = s1;
        part[o + 2 * 25600] = s2;
    }
}

// ---------------------------------------------------------------------------
// Kernel 3: sum 2 channel-group partials + ph_b2 -> params; coords + bilinear
// sample of raw x (3ch) + embed matvec + LN. One wave per token.
// ---------------------------------------------------------------------------
__device__ __forceinline__ float wred64(float v) {
#pragma unroll
    for (int m = 1; m < 64; m <<= 1) v += __shfl_xor(v, m, 64);
    return v;
}

__global__ __launch_bounds__(256) void token_kernel(
    const float* __restrict__ x,
    const float* __restrict__ part,
    const float* __restrict__ ph_b2,
    const float* __restrict__ ew,
    const float* __restrict__ eb,
    const float* __restrict__ lnw,
    const float* __restrict__ lnb,
    float* __restrict__ out) {
    int wid = (blockIdx.x << 2) + (threadIdx.x >> 6);
    int lane = threadIdx.x & 63;
    int b = wid / 25600;
    int r = wid - b * 25600;
    int hp = r / 160, wp = r - hp * 160;

    size_t idx = (size_t)hp * 160 + wp;
    float dx = ph_b2[0], dy = ph_b2[1], ls = ph_b2[2];
#pragma unroll
    for (int g = 0; g < NG; ++g) {
        const float* pg = part + ((size_t)(g * 2 + b) * 3) * 25600 + idx;
        dx += pg[0];
        dy += pg[25600];
        ls += pg[2 * 25600];
    }

    float mx = 2.0f * fast_tanh(dx);
    float my = 2.0f * fast_tanh(dy);
    float s = __builtin_amdgcn_exp2f(1.4426950409f * fast_tanh(ls));
    s = fminf(fmaxf(s, 0.5f), 2.0f);
    float half = 2.0f * s;
    float cx = (float)(wp * 4) + 2.0f;
    float cy = (float)(hp * 4) + 2.0f;
    float x1b = fminf(fmaxf(cx + mx - half, 0.f), 639.f);
    float x2b = fminf(fmaxf(cx + mx + half, 0.f), 639.f);
    float y1b = fminf(fmaxf(cy + my - half, 0.f), 639.f);
    float y2b = fminf(fmaxf(cy + my + half, 0.f), 639.f);

    int sidx = lane >> 2, tap = lane & 3;
    int py = sidx >> 2, px = sidx & 3;
    float xs = x1b + (x2b - x1b) * ((float)px * (1.0f / 3.0f));
    float ys = y1b + (y2b - y1b) * ((float)py * (1.0f / 3.0f));
    float x0f = floorf(xs), y0f = floorf(ys);
    float wx = xs - x0f, wy = ys - y0f;
    int x0 = min(max((int)x0f, 0), 639);
    int y0 = min(max((int)y0f, 0), 639);
    int x1i = min(x0 + 1, 639);
    int y1i = min(y0 + 1, 639);
    int xx = (tap & 1) ? x1i : x0;
    int yy = (tap & 2) ? y1i : y0;
    float wgt = ((tap & 1) ? wx : 1.f - wx) * ((tap & 2) ? wy : 1.f - wy);

    const float* xbp = x + (size_t)b * 3 * 409600;
    int off = yy * 640 + xx;
    float a0 = wgt * xbp[off];
    float a1 = wgt * xbp[409600 + off];
    float a2 = wgt * xbp[819200 + off];

    a0 = wred64(a0) * (1.0f / 16.0f);
    a1 = wred64(a1) * (1.0f / 16.0f);
    a2 = wred64(a2) * (1.0f / 16.0f);

    float t1 = eb[lane] + ew[lane * 3] * a0 + ew[lane * 3 + 1] * a1 + ew[lane * 3 + 2] * a2;
    float t2 = 0.f;
    if (lane < 32) {
        int d = 64 + lane;
        t2 = eb[d] + ew[d * 3] * a0 + ew[d * 3 + 1] * a1 + ew[d * 3 + 2] * a2;
    }
    float sum = t1 + ((lane < 32) ? t2 : 0.f);
    float mu = wred64(sum) * (1.0f / 96.0f);
    float d1 = t1 - mu, d2 = t2 - mu;
    float qq = d1 * d1 + ((lane < 32) ? d2 * d2 : 0.f);
    float var = wred64(qq) * (1.0f / 96.0f);
    float rs = 1.0f / sqrtf(var + 1e-5f);

    size_t ob = ((size_t)b * 25600 + idx) * 96;
    out[ob + lane] = d1 * rs * lnw[lane] + lnb[lane];
    if (lane < 32) {
        int d = 64 + lane;
        out[ob + d] = d2 * rs * lnw[d] + lnb[d];
    }
    if (lane == 0) {
        out[(size_t)4915200 + (size_t)b * 25600 + idx] = s;
    }
}

// ---------------------------------------------------------------------------
extern "C" void kernel_launch(void* const* d_in, const int* in_sizes, int n_in,
                              void* d_out, int out_size, void* d_ws, size_t ws_size,
                              hipStream_t stream) {
    const float* x       = (const float*)d_in[0];
    const float* embed_w = (const float*)d_in[1];
    const float* embed_b = (const float*)d_in[2];
    const float* ph_w1   = (const float*)d_in[3];
    const float* ph_b1   = (const float*)d_in[4];
    const float* ph_w2   = (const float*)d_in[5];
    const float* ph_b2   = (const float*)d_in[6];
    const float* ln_w    = (const float*)d_in[7];
    const float* ln_b    = (const float*)d_in[8];

    float* ws = (float*)d_ws;
    float* w1h    = ws;              // 96*16 = 1536 floats (packed weights)
    float* B1f    = ws + 1536;       // 864
    float* part   = ws + 2400;       // NG*2*3*25600 = 307200 floats

    fold_kernel<<<1, 128, 0, stream>>>(ph_w1, embed_w, embed_b, ph_b1, w1h, B1f);
    params_kernel<<<3200 * NG, 256, 0, stream>>>(x, w1h, B1f, ph_b1, ph_w2, part);
    token_kernel<<<12800, 256, 0, stream>>>(x, part, ph_b2, embed_w, embed_b, ln_w, ln_b, (float*)d_out);
}

// Round 13
// 124.485 us; speedup vs baseline: 1.1262x; 1.1262x over previous
//
#include <hip/hip_runtime.h>
#include <cstdint>
#include <cstddef>

#define IMGW 640
#define BATCH 2

typedef float f32x4 __attribute__((ext_vector_type(4)));
typedef short s16x8 __attribute__((ext_vector_type(8)));

__device__ __forceinline__ uint32_t bf16rne(float f) {
    uint32_t u = __builtin_bit_cast(uint32_t, f);
    u += 0x7FFFu + ((u >> 16) & 1u);
    return u >> 16;
}
__device__ __forceinline__ uint32_t pk2(uint32_t lo, uint32_t hi) { return lo | (hi << 16); }
__device__ __forceinline__ float blo(uint32_t u) { return __builtin_bit_cast(float, u << 16); }
__device__ __forceinline__ float bhi(uint32_t u) { return __builtin_bit_cast(float, u & 0xFFFF0000u); }

// tiny-|h| GELU: h*(0.5 + phi0*h*(1 - h^2/6)), clamp poly input to |h|<=1.
__device__ __forceinline__ float gelu_poly(float h) {
    float hc = fminf(fmaxf(h, -1.0f), 1.0f);
    float q = fmaf(hc * hc, -0.1666666667f, 1.0f);
    float r = fmaf(0.3989422804f * hc, q, 0.5f);
    return h * r;
}

__device__ __forceinline__ float fast_tanh(float t) {
    float u = __builtin_amdgcn_exp2f(2.8853900818f * t);    // e^{2t}
    return 1.0f - 2.0f * __builtin_amdgcn_rcpf(u + 1.0f);
}

__device__ __forceinline__ float wred64(float v) {
#pragma unroll
    for (int m = 1; m < 64; m <<= 1) v += __shfl_xor(v, m, 64);
    return v;
}

// ---------------------------------------------------------------------------
// Kernel 1: fold embed into ph_w1; emit MFMA A-fragments (bf16, slot->k map
// psi(g,j)=g*8+j, k = c*9 + dy*3 + dx, taps 27..31 zero), bias_int, and
// border inclusion-exclusion tables R3 (missing-row), C3 (missing-col),
// B9t (corner), all transposed [j][e] for float4 e-reads.
// ---------------------------------------------------------------------------
__global__ void fold_kernel(const float* __restrict__ ph_w1,
                            const float* __restrict__ embed_w,
                            const float* __restrict__ embed_b,
                            const float* __restrict__ ph_b1,
                            float* __restrict__ w1pk,
                            float* __restrict__ bias_int,
                            float* __restrict__ R3,
                            float* __restrict__ C3,
                            float* __restrict__ B9t) {
    int e = blockIdx.x * 128 + threadIdx.x;
    if (e >= 96) return;
    float g[27];   // [t*3+c], t = spatial tap 0..8
    float bf[9];
#pragma unroll
    for (int k = 0; k < 27; ++k) g[k] = 0.f;
#pragma unroll
    for (int k = 0; k < 9; ++k) bf[k] = 0.f;
    for (int c96 = 0; c96 < 96; ++c96) {
        const float* w = ph_w1 + e * 864 + c96 * 9;
        float e0 = embed_w[c96 * 3], e1 = embed_w[c96 * 3 + 1], e2 = embed_w[c96 * 3 + 2];
        float eb = embed_b[c96];
#pragma unroll
        for (int t = 0; t < 9; ++t) {
            float wk = w[t];
            g[t * 3 + 0] = fmaf(wk, e0, g[t * 3 + 0]);
            g[t * 3 + 1] = fmaf(wk, e1, g[t * 3 + 1]);
            g[t * 3 + 2] = fmaf(wk, e2, g[t * 3 + 2]);
            bf[t] = fmaf(wk, eb, bf[t]);
        }
    }
    float bi = ph_b1[e];
#pragma unroll
    for (int t = 0; t < 9; ++t) bi += bf[t];
    bias_int[e] = bi;
#pragma unroll
    for (int dy = 0; dy < 3; ++dy)
        R3[dy * 96 + e] = bf[dy * 3] + bf[dy * 3 + 1] + bf[dy * 3 + 2];
#pragma unroll
    for (int dx = 0; dx < 3; ++dx)
        C3[dx * 96 + e] = bf[dx] + bf[3 + dx] + bf[6 + dx];
#pragma unroll
    for (int t = 0; t < 9; ++t) B9t[t * 96 + e] = bf[t];

    // A fragments: lane = gg*16 + (e&15) holds k-slots gg*8+j (j=0..7) of row e&15.
    int eb2 = e >> 4, el = e & 15;
#pragma unroll
    for (int gg = 0; gg < 4; ++gg)
#pragma unroll
        for (int d = 0; d < 4; ++d) {
            int k0 = gg * 8 + 2 * d, k1 = k0 + 1;
            uint32_t lo = 0, hi = 0;
            if (k0 < 27) { int c = k0 / 9, t = k0 - 9 * c; lo = bf16rne(g[t * 3 + c]); }
            if (k1 < 27) { int c = k1 / 9, t = k1 - 9 * c; hi = bf16rne(g[t * 3 + c]); }
            w1pk[(size_t)(eb2 * 64 + gg * 16 + el) * 4 + d] =
                __builtin_bit_cast(float, pk2(lo, hi));
        }
}

// ---------------------------------------------------------------------------
// Kernel 2: MFMA conv1 (16x16x32 bf16: 16 e x 16 px, one patch per MFMA col
// set) + poly GELU + conv2 as per-lane FMA + wred64. Block = 16x16 px = 16
// patches, 4 waves x 4 patches. B im2col packed in LDS with the SAME slot->k
// map as A (any consistent bijection is correct since phi_A == phi_B).
// ---------------------------------------------------------------------------
__global__ __launch_bounds__(256) void params_kernel(
    const float* __restrict__ x,
    const float* __restrict__ w1pk,
    const float* __restrict__ bias_int,
    const float* __restrict__ R3,
    const float* __restrict__ C3,
    const float* __restrict__ B9t,
    const float* __restrict__ ph_w2,
    const float* __restrict__ ph_b2,
    float* __restrict__ params) {
    __shared__ __align__(16) uint32_t xs2[4096];      // [patch][pi][16 dw] bf16 im2col, 16KB
    __shared__ __align__(16) uint32_t w2pk[16 * 196]; // [pi][eblk][g][8 dw] bf16 conv2 wts, 12.25KB

    int bid = blockIdx.x;                 // 2 * 40 * 40
    int b = bid / 1600;
    int rem = bid - b * 1600;
    int th = rem / 40, tw = rem - th * 40;
    int y0 = th * 16, x0 = tw * 16;
    int tid = threadIdx.x;

    // ---- stage im2col: one pixel per thread ----
    {
        int p = tid >> 4, pi = tid & 15;
        int gy = y0 + ((p >> 2) << 2) + (pi >> 2);
        int gx = x0 + ((p & 3) << 2) + (pi & 3);
        const float* xb = x + (size_t)b * 3 * 409600;
        uint32_t v[27];
#pragma unroll
        for (int c = 0; c < 3; ++c)
#pragma unroll
            for (int dy = 0; dy < 3; ++dy)
#pragma unroll
                for (int dx = 0; dx < 3; ++dx) {
                    int iy = gy + dy - 1, ix = gx + dx - 1;
                    float xv = (iy >= 0 && iy < IMGW && ix >= 0 && ix < IMGW)
                                   ? xb[c * 409600 + iy * 640 + ix] : 0.f;
                    v[c * 9 + dy * 3 + dx] = bf16rne(xv);
                }
        int base = p * 256 + pi * 16;
#pragma unroll
        for (int i4 = 0; i4 < 4; ++i4) {
            uint32_t dw[4];
#pragma unroll
            for (int j = 0; j < 4; ++j) {
                int k0 = i4 * 8 + 2 * j, k1 = k0 + 1;
                uint32_t lo = (k0 < 27) ? v[k0] : 0u;
                uint32_t hi = (k1 < 27) ? v[k1] : 0u;
                dw[j] = pk2(lo, hi);
            }
            *reinterpret_cast<uint4*>(&xs2[base + ((i4 ^ (pi & 3)) << 2)]) =
                make_uint4(dw[0], dw[1], dw[2], dw[3]);
        }
    }
    // ---- stage conv2 weights (bf16 pairs over e) ----
    for (int l = tid; l < 2304; l += 256) {
        int d = l % 6; int rest = l / 6;
        int g = rest & 3; rest >>= 2;
        int eblk = rest % 6; int pi = rest / 6;
        int ch = d >> 1, ep = d & 1;
        int e0 = eblk * 16 + g * 4 + ep * 2;
        uint32_t lo = bf16rne(ph_w2[ch * 1536 + e0 * 16 + pi]);
        uint32_t hi = bf16rne(ph_w2[ch * 1536 + (e0 + 1) * 16 + pi]);
        w2pk[pi * 196 + eblk * 32 + g * 8 + d] = pk2(lo, hi);
    }
    __syncthreads();

    int lane = tid & 63;
    int wv = tid >> 6;
    int pi = lane & 15, g = lane >> 4;
    bool borderBlk = (th == 0) || (tw == 0) || (th == 39) || (tw == 39);

    const s16x8* Afrag = reinterpret_cast<const s16x8*>(w1pk);
    const f32x4* biasv = reinterpret_cast<const f32x4*>(bias_int);
    f32x4 zz = {0.f, 0.f, 0.f, 0.f};

#pragma unroll
    for (int pp = 0; pp < 4; ++pp) {
        int p = wv * 4 + pp;
        s16x8 Bf = *reinterpret_cast<const s16x8*>(
            &xs2[p * 256 + pi * 16 + ((g ^ (pi & 3)) << 2)]);
        float fy = 0.f, fx = 0.f; int dyM = 0, dxM = 0;
        if (borderBlk) {
            int gy = y0 + ((p >> 2) << 2) + (pi >> 2);
            int gx = x0 + ((p & 3) << 2) + (pi & 3);
            if (gy == 0) { fy = 1.f; dyM = 0; } else if (gy == 639) { fy = 1.f; dyM = 2; }
            if (gx == 0) { fx = 1.f; dxM = 0; } else if (gx == 639) { fx = 1.f; dxM = 2; }
        }
        float s0 = 0.f, s1 = 0.f, s2 = 0.f;
#pragma unroll
        for (int eb = 0; eb < 6; ++eb) {
            s16x8 Av = Afrag[eb * 64 + lane];
            f32x4 bias = biasv[eb * 4 + g];
            if (borderBlk) {
                f32x4 Rv = reinterpret_cast<const f32x4*>(R3 + dyM * 96)[eb * 4 + g];
                f32x4 Cv = reinterpret_cast<const f32x4*>(C3 + dxM * 96)[eb * 4 + g];
                f32x4 Bv = reinterpret_cast<const f32x4*>(B9t + (dyM * 3 + dxM) * 96)[eb * 4 + g];
                bias = bias - (fy * Rv + fx * Cv - (fy * fx) * Bv);
            }
            int wb = pi * 196 + eb * 32 + g * 8;
            uint4 wA = *reinterpret_cast<const uint4*>(&w2pk[wb]);
            uint2 wB2 = *reinterpret_cast<const uint2*>(&w2pk[wb + 4]);

            f32x4 D = __builtin_amdgcn_mfma_f32_16x16x32_bf16(Av, Bf, zz, 0, 0, 0);
            float g0 = gelu_poly(D[0] + bias[0]);
            float g1 = gelu_poly(D[1] + bias[1]);
            float g2 = gelu_poly(D[2] + bias[2]);
            float g3 = gelu_poly(D[3] + bias[3]);

            s0 = fmaf(g0, blo(wA.x), s0); s0 = fmaf(g1, bhi(wA.x), s0);
            s0 = fmaf(g2, blo(wA.y), s0); s0 = fmaf(g3, bhi(wA.y), s0);
            s1 = fmaf(g0, blo(wA.z), s1); s1 = fmaf(g1, bhi(wA.z), s1);
            s1 = fmaf(g2, blo(wA.w), s1); s1 = fmaf(g3, bhi(wA.w), s1);
            s2 = fmaf(g0, blo(wB2.x), s2); s2 = fmaf(g1, bhi(wB2.x), s2);
            s2 = fmaf(g2, blo(wB2.y), s2); s2 = fmaf(g3, bhi(wB2.y), s2);
        }
        s0 = wred64(s0); s1 = wred64(s1); s2 = wred64(s2);
        if (lane == 0) {
            int hp = th * 4 + (p >> 2), wp = tw * 4 + (p & 3);
            size_t o = (size_t)b * 3 * 25600 + (size_t)hp * 160 + wp;
            params[o]             = s0 + ph_b2[0];
            params[o + 25600]     = s1 + ph_b2[1];
            params[o + 2 * 25600] = s2 + ph_b2[2];
        }
    }
}

// ---------------------------------------------------------------------------
// Kernel 3: coords + bilinear sample of raw x (3ch) + embed matvec + LN.
// One wave per token. (Unchanged from R10.)
// ---------------------------------------------------------------------------
__global__ __launch_bounds__(256) void token_kernel(
    const float* __restrict__ x,
    const float* __restrict__ params,
    const float* __restrict__ ew,
    const float* __restrict__ eb,
    const float* __restrict__ lnw,
    const float* __restrict__ lnb,
    float* __restrict__ out) {
    int wid = (blockIdx.x << 2) + (threadIdx.x >> 6);
    int lane = threadIdx.x & 63;
    int b = wid / 25600;
    int r = wid - b * 25600;
    int hp = r / 160, wp = r - hp * 160;

    size_t idx = (size_t)hp * 160 + wp;
    size_t pbase = (size_t)b * 3 * 25600 + idx;
    float dx = params[pbase];
    float dy = params[pbase + 25600];
    float ls = params[pbase + 2 * 25600];

    float mx = 2.0f * fast_tanh(dx);
    float my = 2.0f * fast_tanh(dy);
    float s = __builtin_amdgcn_exp2f(1.4426950409f * fast_tanh(ls));
    s = fminf(fmaxf(s, 0.5f), 2.0f);
    float half = 2.0f * s;
    float cx = (float)(wp * 4) + 2.0f;
    float cy = (float)(hp * 4) + 2.0f;
    float x1b = fminf(fmaxf(cx + mx - half, 0.f), 639.f);
    float x2b = fminf(fmaxf(cx + mx + half, 0.f), 639.f);
    float y1b = fminf(fmaxf(cy + my - half, 0.f), 639.f);
    float y2b = fminf(fmaxf(cy + my + half, 0.f), 639.f);

    int sidx = lane >> 2, tap = lane & 3;
    int py = sidx >> 2, px = sidx & 3;
    float xs = x1b + (x2b - x1b) * ((float)px * (1.0f / 3.0f));
    float ys = y1b + (y2b - y1b) * ((float)py * (1.0f / 3.0f));
    float x0f = floorf(xs), y0f = floorf(ys);
    float wx = xs - x0f, wy = ys - y0f;
    int x0 = min(max((int)x0f, 0), 639);
    int y0 = min(max((int)y0f, 0), 639);
    int x1i = min(x0 + 1, 639);
    int y1i = min(y0 + 1, 639);
    int xx = (tap & 1) ? x1i : x0;
    int yy = (tap & 2) ? y1i : y0;
    float wgt = ((tap & 1) ? wx : 1.f - wx) * ((tap & 2) ? wy : 1.f - wy);

    const float* xbp = x + (size_t)b * 3 * 409600;
    int off = yy * 640 + xx;
    float a0 = wgt * xbp[off];
    float a1 = wgt * xbp[409600 + off];
    float a2 = wgt * xbp[819200 + off];

    a0 = wred64(a0) * (1.0f / 16.0f);
    a1 = wred64(a1) * (1.0f / 16.0f);
    a2 = wred64(a2) * (1.0f / 16.0f);

    float t1 = eb[lane] + ew[lane * 3] * a0 + ew[lane * 3 + 1] * a1 + ew[lane * 3 + 2] * a2;
    float t2 = 0.f;
    if (lane < 32) {
        int d = 64 + lane;
        t2 = eb[d] + ew[d * 3] * a0 + ew[d * 3 + 1] * a1 + ew[d * 3 + 2] * a2;
    }
    float sum = t1 + ((lane < 32) ? t2 : 0.f);
    float mu = wred64(sum) * (1.0f / 96.0f);
    float d1 = t1 - mu, d2 = t2 - mu;
    float qq = d1 * d1 + ((lane < 32) ? d2 * d2 : 0.f);
    float var = wred64(qq) * (1.0f / 96.0f);
    float rs = 1.0f / sqrtf(var + 1e-5f);

    size_t ob = ((size_t)b * 25600 + idx) * 96;
    out[ob + lane] = d1 * rs * lnw[lane] + lnb[lane];
    if (lane < 32) {
        int d = 64 + lane;
        out[ob + d] = d2 * rs * lnw[d] + lnb[d];
    }
    if (lane == 0) {
        out[(size_t)4915200 + (size_t)b * 25600 + idx] = s;
    }
}

// ---------------------------------------------------------------------------
extern "C" void kernel_launch(void* const* d_in, const int* in_sizes, int n_in,
                              void* d_out, int out_size, void* d_ws, size_t ws_size,
                              hipStream_t stream) {
    const float* x       = (const float*)d_in[0];
    const float* embed_w = (const float*)d_in[1];
    const float* embed_b = (const float*)d_in[2];
    const float* ph_w1   = (const float*)d_in[3];
    const float* ph_b1   = (const float*)d_in[4];
    const float* ph_w2   = (const float*)d_in[5];
    const float* ph_b2   = (const float*)d_in[6];
    const float* ln_w    = (const float*)d_in[7];
    const float* ln_b    = (const float*)d_in[8];

    float* ws = (float*)d_ws;
    float* w1pk     = ws;            // 1536 floats: A-fragments (bf16x2 dwords)
    float* bias_int = ws + 1536;     // 96
    float* R3       = ws + 1632;     // 288
    float* C3       = ws + 1920;     // 288
    float* B9t      = ws + 2208;     // 864
    float* params   = ws + 3072;     // 2*3*25600 = 153600

    fold_kernel<<<1, 128, 0, stream>>>(ph_w1, embed_w, embed_b, ph_b1,
                                       w1pk, bias_int, R3, C3, B9t);
    params_kernel<<<3200, 256, 0, stream>>>(x, w1pk, bias_int, R3, C3, B9t,
                                            ph_w2, ph_b2, params);
    token_kernel<<<12800, 256, 0, stream>>>(x, params, embed_w, embed_b,
                                            ln_w, ln_b, (float*)d_out);
}